// Round 3
// baseline (666.942 us; speedup 1.0000x reference)
//
#include <hip/hip_runtime.h>

// Problem constants
#define B_    1024
#define S_    64
#define D_    768
#define POOL_ 30
#define TOPK_ 4
#define SEQ_  68
#define CT_   64

// d_out element offsets (f32)
#define OUT_NP    50331648ull              // B*CT*D
#define OUT_RSIM  50331648ull
#define OUT_SIM   50331649ull
#define OUT_IDX   50362369ull              // OUT_SIM + B*POOL

typedef short s16x8 __attribute__((ext_vector_type(8)));
typedef float f32x4 __attribute__((ext_vector_type(4)));
typedef unsigned short u16;

__device__ __forceinline__ u16 f2bf(float f){
  unsigned u = __float_as_uint(f);
  u += 0x7fff + ((u >> 16) & 1);           // RNE
  return (u16)(u >> 16);
}

// Swizzled Arows element (row 0..63, col 0..767 in u16 units), stride 776 u16.
// 16B-granule ROTATE within each 128B window by (row&7): uniform bank spread
// for the gemm's 16-lane row-slice ds_read_b128 (16B-aligned strides are an
// inherent 8-way conflict otherwise; padding cannot fix, rotation can).
__device__ __forceinline__ int ar_idx(int row, int col){
  return row*776 + (col & ~63) + ((((col >> 3) + row) & 7) << 3) + (col & 7);
}

// ---------------------------------------------------------------------------
// K0a: prompt norms + small weights packed into MFMA-fragment order.
// ---------------------------------------------------------------------------
__global__ void prep_small(const float* __restrict__ prompt,
                           const float* __restrict__ w1a,
                           const float* __restrict__ w1b,
                           float* __restrict__ pnorm2,
                           u16* __restrict__ w1aT, u16* __restrict__ w1bT){
  int t = threadIdx.x;
  if (blockIdx.x == 0){
    if (t < 240){
      int j = t >> 3, seg = t & 7;
      float s = 0.f;
      for (int d = seg*96; d < seg*96 + 96; ++d){ float v = prompt[j*768 + d]; s += v*v; }
      #pragma unroll
      for (int m = 1; m < 8; m <<= 1) s += __shfl_xor(s, m);
      if (seg == 0) pnorm2[j] = rsqrtf(fmaxf(s, 1e-12f));
    }
  } else if (blockIdx.x == 1){
    // w1a packed: 4 nt-tiles x 3 ks-tiles (K zero-padded 68->96)
    for (int e = t; e < 6144; e += 256){
      int frag = e >> 3, el = e & 7;
      int lane = frag & 63, tile = frag >> 6;     // tile = nt*3 + ks
      int nt = tile / 3, ks = tile % 3;
      int k  = ks*32 + (lane >> 4)*8 + el;
      int ct = nt*16 + (lane & 15);
      w1aT[e] = f2bf(k < SEQ_ ? w1a[k*64 + ct] : 0.f);
    }
  } else {
    // w1b packed: 4 nt-tiles x 2 ks-tiles
    for (int e = t; e < 4096; e += 256){
      int frag = e >> 3, el = e & 7;
      int lane = frag & 63, tile = frag >> 6;     // tile = nt*2 + ks
      int nt = tile >> 1, ks = tile & 1;
      int k  = ks*32 + (lane >> 4)*8 + el;
      int n  = nt*16 + (lane & 15);
      w1bT[e] = f2bf(w1b[k*64 + n]);
    }
  }
}

// ---------------------------------------------------------------------------
// K0b: pack 768x768 f32 weights into bf16 MFMA-fragment order.
// Wpk element ((ntg*24 + ks)*64 + lane)*8 + e = w[k][n],
//   k = ks*32 + (lane>>4)*8 + e,  n = ntg*16 + (lane&15)
// ---------------------------------------------------------------------------
__global__ void pack_w(const float* __restrict__ w2a,
                       const float* __restrict__ w2b,
                       u16* __restrict__ Wpka, u16* __restrict__ Wpkb){
  int lane = threadIdx.x;                          // 64
  int ntg = blockIdx.x, ks = blockIdx.y;           // 48 x 24
  const float* w = blockIdx.z ? w2b : w2a;
  u16* wp = (blockIdx.z ? Wpkb : Wpka) + ((size_t)(ntg*24 + ks)*64 + lane)*8;
  int n  = ntg*16 + (lane & 15);
  int k0 = ks*32 + (lane >> 4)*8;
  #pragma unroll
  for (int e = 0; e < 8; ++e) wp[e] = f2bf(w[(size_t)(k0 + e)*768 + n]);
}

// ---------------------------------------------------------------------------
// fused mlp_2 gemm: 64 rows x (N=768, K=768), A in swizzled LDS Arows.
// 8 waves; wave wv owns all 64 rows x cols [wv*96, wv*96+96).
// 3-buffer weight prefetch (distance 2): loads issue BEFORE the MFMA cluster.
// ---------------------------------------------------------------------------
template<bool FINAL>
__device__ __forceinline__ void gemm_ln_768(
    const u16* __restrict__ Wpk, const float* __restrict__ bias,
    const float* __restrict__ g, const float* __restrict__ be,
    u16* __restrict__ Arows, float (*red)[64][8], float (*redt)[64],
    float* __restrict__ outp, int row0, int t)
{
  int wv = t >> 6, lane = t & 63, quad = lane >> 4, l15 = lane & 15;
  int h = l15 & 7;                               // (row & 7) for rows mt*16+l15
  f32x4 acc[4][6];
  #pragma unroll
  for (int mt = 0; mt < 4; ++mt)
    #pragma unroll
    for (int nt = 0; nt < 6; ++nt) acc[mt][nt] = (f32x4){0.f,0.f,0.f,0.f};

  const u16* wbase = Wpk + (size_t)wv*73728 + (size_t)lane*8;

  // A-read bases: addr(ks,mt) = (ks&1 ? Ap1 : Ap0)[mt] + (ks>>1)*64 u16
  const u16* Ap0[4]; const u16* Ap1[4];
  #pragma unroll
  for (int mt = 0; mt < 4; ++mt){
    int rb = (mt*16 + l15)*776;
    Ap0[mt] = Arows + rb + (((quad     + h) & 7) << 3);
    Ap1[mt] = Arows + rb + (((quad + 4 + h) & 7) << 3);
  }

  s16x8 bX[6], bY[6], bZ[6];
  #pragma unroll
  for (int nt = 0; nt < 6; ++nt) bX[nt] = *(const s16x8*)(wbase + nt*12288);
  #pragma unroll
  for (int nt = 0; nt < 6; ++nt) bY[nt] = *(const s16x8*)(wbase + nt*12288 + 512);

#define GSTEP(CUR, PRE, KS)                                                    \
  {                                                                            \
    if ((KS)+2 < 24){                                                          \
      _Pragma("unroll")                                                        \
      for (int nt = 0; nt < 6; ++nt)                                           \
        PRE[nt] = *(const s16x8*)(wbase + nt*12288 + ((KS)+2)*512);            \
    }                                                                          \
    s16x8 a_[4];                                                               \
    _Pragma("unroll")                                                          \
    for (int mt = 0; mt < 4; ++mt)                                             \
      a_[mt] = *(const s16x8*)(( ((KS)&1) ? Ap1[mt] : Ap0[mt] ) + ((KS)>>1)*64);\
    _Pragma("unroll")                                                          \
    for (int nt = 0; nt < 6; ++nt){                                            \
      _Pragma("unroll")                                                        \
      for (int mt = 0; mt < 4; ++mt)                                           \
        acc[mt][nt] = __builtin_amdgcn_mfma_f32_16x16x32_bf16(a_[mt], CUR[nt], acc[mt][nt], 0, 0, 0); \
    }                                                                          \
  }

  #pragma unroll
  for (int kp = 0; kp < 8; ++kp){
    GSTEP(bX, bZ, kp*3+0)
    GSTEP(bY, bX, kp*3+1)
    GSTEP(bZ, bY, kp*3+2)
  }
#undef GSTEP

  // bias + relu + per-row partial LN sums (this wave covers 96 of 768 cols)
  float s1[4][4], s2[4][4];
  #pragma unroll
  for (int mt = 0; mt < 4; ++mt)
    #pragma unroll
    for (int i = 0; i < 4; ++i){ s1[mt][i] = 0.f; s2[mt][i] = 0.f; }
  #pragma unroll
  for (int nt = 0; nt < 6; ++nt){
    float bb = bias[wv*96 + nt*16 + l15];
    #pragma unroll
    for (int mt = 0; mt < 4; ++mt){
      #pragma unroll
      for (int i = 0; i < 4; ++i){
        float v = fmaxf(acc[mt][nt][i] + bb, 0.f);
        acc[mt][nt][i] = v; s1[mt][i] += v; s2[mt][i] += v*v;
      }
    }
  }
  #pragma unroll
  for (int mt = 0; mt < 4; ++mt){
    #pragma unroll
    for (int i = 0; i < 4; ++i){
      #pragma unroll
      for (int m = 1; m < 16; m <<= 1){
        s1[mt][i] += __shfl_xor(s1[mt][i], m);
        s2[mt][i] += __shfl_xor(s2[mt][i], m);
      }
    }
  }
  if (l15 == 0){
    #pragma unroll
    for (int mt = 0; mt < 4; ++mt)
      #pragma unroll
      for (int i = 0; i < 4; ++i){
        int row = mt*16 + quad*4 + i;
        red[0][row][wv] = s1[mt][i]; red[1][row][wv] = s2[mt][i];
      }
  }
  __syncthreads();
  if (t < 128){
    int r = t >> 1, p = t & 1;
    float s = 0.f;
    #pragma unroll
    for (int w = 0; w < 8; ++w) s += red[p][r][w];
    redt[p][r] = s;
  }
  __syncthreads();
  #pragma unroll
  for (int mt = 0; mt < 4; ++mt){
    #pragma unroll
    for (int i = 0; i < 4; ++i){
      int row = mt*16 + quad*4 + i;
      float mean = redt[0][row]*(1.f/768.f);
      float var  = redt[1][row]*(1.f/768.f) - mean*mean;
      float rs   = rsqrtf(var + 1e-5f);
      #pragma unroll
      for (int nt = 0; nt < 6; ++nt){
        int col = wv*96 + nt*16 + l15;
        float v = (acc[mt][nt][i] - mean)*rs*g[col] + be[col];
        if (FINAL) outp[(size_t)(row0 + row)*768 + col] = v;
        else       Arows[ar_idx(row, col)] = f2bf(v);
      }
    }
  }
}

// ---------------------------------------------------------------------------
// FUSED: one block = one batch. sim/topk -> mlp_1 (6 chunks) -> mlp_2.
// Removes Tg round-trip (200 MB), second HBM read of xe, inter-kernel gaps.
// ---------------------------------------------------------------------------
__global__ __launch_bounds__(512, 2)
void fused(const float* __restrict__ xe, const float* __restrict__ prompt,
           const float* __restrict__ pnorm2,
           const u16* __restrict__ w1aT, const u16* __restrict__ w1bT,
           const float* __restrict__ b1a, const float* __restrict__ g1a, const float* __restrict__ be1a,
           const float* __restrict__ b1b, const float* __restrict__ g1b, const float* __restrict__ be1b,
           const u16* __restrict__ Wpka, const u16* __restrict__ Wpkb,
           const float* __restrict__ b2a, const float* __restrict__ g2a, const float* __restrict__ be2a,
           const float* __restrict__ b2b, const float* __restrict__ g2b, const float* __restrict__ be2b,
           float* __restrict__ out)
{
  __shared__ __align__(16) u16 Arows[64*776];            // 99328 B, swizzled
  __shared__ __align__(16) unsigned char scr[43136];     // pass1: ps+xm4s / pass2: As_pk+A2s
  __shared__ float red[2][64][8];
  __shared__ float redt[2][64];
  __shared__ float simv[30];
  __shared__ float rsx_sh;
  __shared__ int   idxs[4];

  int b = blockIdx.x, t = threadIdx.x;
  int lane = t & 63, wv = t >> 6, quad = lane >> 4, l15 = lane & 15;

  // ================= pass 1: mean, l2-norm, sims, top-4 =================
  {
    f32x4 (*ps)[192] = (f32x4(*)[192])scr;               // 8 x 192 x 16B
    f32x4* xm4s = (f32x4*)(scr + 24576);                 // 192 x 16B
    const f32x4* xrow = (const f32x4*)(xe + (size_t)b*49152);
    f32x4 a0 = {0.f,0.f,0.f,0.f}, a1 = a0, a2 = a0;
    #pragma unroll
    for (int r = 0; r < 8; ++r){
      const f32x4* rp = xrow + (size_t)(wv*8 + r)*192;
      a0 += rp[lane]; a1 += rp[lane + 64]; a2 += rp[lane + 128];
    }
    ps[wv][lane] = a0; ps[wv][lane + 64] = a1; ps[wv][lane + 128] = a2;
    __syncthreads();
    if (t < 192){
      f32x4 s = ps[0][t];
      #pragma unroll
      for (int w = 1; w < 8; ++w) s += ps[w][t];
      s *= (1.f/64.f);
      xm4s[t] = s;
    }
    __syncthreads();
    if (wv == 0){
      f32x4 v0 = xm4s[lane], v1 = xm4s[lane + 64], v2 = xm4s[lane + 128];
      float n = v0[0]*v0[0]+v0[1]*v0[1]+v0[2]*v0[2]+v0[3]*v0[3]
              + v1[0]*v1[0]+v1[1]*v1[1]+v1[2]*v1[2]+v1[3]*v1[3]
              + v2[0]*v2[0]+v2[1]*v2[1]+v2[2]*v2[2]+v2[3]*v2[3];
      #pragma unroll
      for (int m = 1; m < 64; m <<= 1) n += __shfl_xor(n, m);
      if (lane == 0) rsx_sh = rsqrtf(fmaxf(n, 1e-12f));
    }
    __syncthreads();
    if (t < 240){
      int j = t >> 3, seg = t & 7;
      const f32x4* pj = (const f32x4*)(prompt + j*768) + seg*24;
      const f32x4* xm = xm4s + seg*24;
      float s = 0.f;
      #pragma unroll
      for (int i = 0; i < 24; ++i){
        f32x4 p = pj[i], x = xm[i];
        s += p[0]*x[0] + p[1]*x[1] + p[2]*x[2] + p[3]*x[3];
      }
      #pragma unroll
      for (int m = 1; m < 8; m <<= 1) s += __shfl_xor(s, m);
      if (seg == 0){
        float sim = s * rsx_sh * pnorm2[j];
        out[OUT_SIM + (size_t)b*30 + j] = sim;
        simv[j] = sim;
      }
    }
    __syncthreads();
    if (t == 0){
      float racc = 0.f;
      for (int k = 0; k < 4; ++k){
        float best = -1e30f; int bi = 0;
        for (int j = 0; j < 30; ++j){ float v = simv[j]; if (v > best){ best = v; bi = j; } }
        simv[bi] = -1e30f;
        idxs[k] = bi;
        out[OUT_IDX + (size_t)b*4 + k] = (float)bi;
        racc += best;
      }
      atomicAdd(&out[OUT_RSIM], racc * (1.f/1024.f));
    }
    __syncthreads();
  }

  // ================= pass 2: mlp_1, 6 chunks of 128 d =================
  {
    u16* As_pk     = (u16*)scr;                          // 8 x 1544 u16 = 24704 B
    u16 (*A2s)[72] = (u16(*)[72])(scr + 24704);          // 128 x 72 = 18432 B

    // preload block-invariant small-weight fragments into registers
    s16x8 wa[12], wb[8];
    #pragma unroll
    for (int f = 0; f < 12; ++f) wa[f] = *(const s16x8*)(w1aT + (f*64 + lane)*8);
    #pragma unroll
    for (int f = 0; f < 8; ++f)  wb[f] = *(const s16x8*)(w1bT + (f*64 + lane)*8);

    int mrow = wv*16 + l15;
    for (int c6 = 0; c6 < 6; ++c6){
      int d0 = c6*128;
      // stage X^T chunk into fragment-packed LDS (bf16), K zero-padded 68->96
      #pragma unroll
      for (int p = 0; p < 12; ++p){
        int item = t + 512*p;                  // 48 jp x 128 dd
        int dd = item & 127, jp = item >> 7;
        int j = jp << 1;
        float v0 = 0.f, v1 = 0.f;
        if (j < 4){
          v0 = prompt[(size_t)idxs[j    ]*768 + d0 + dd];
          v1 = prompt[(size_t)idxs[j + 1]*768 + d0 + dd];
        } else if (j < 68){
          const float* xp = xe + ((size_t)b*64 + (j-4))*768 + d0 + dd;
          v0 = xp[0];
          v1 = xp[768];
        }
        unsigned pk = (unsigned)f2bf(v0) | ((unsigned)f2bf(v1) << 16);
        int idx16 = (dd>>4)*1544 + (j>>5)*512 + ((j>>3)&3)*128 + (dd&15)*8 + (j&7);
        *(unsigned*)&As_pk[idx16] = pk;
      }
      __syncthreads();

      // mm1: (128 x 96) @ (96 x 64)
      f32x4 acc[4];
      #pragma unroll
      for (int nt = 0; nt < 4; ++nt) acc[nt] = (f32x4){0.f,0.f,0.f,0.f};
      #pragma unroll
      for (int ks = 0; ks < 3; ++ks){
        s16x8 a = *(const s16x8*)&As_pk[wv*1544 + ks*512 + lane*8];
        #pragma unroll
        for (int nt = 0; nt < 4; ++nt)
          acc[nt] = __builtin_amdgcn_mfma_f32_16x16x32_bf16(a, wa[nt*3 + ks], acc[nt], 0, 0, 0);
      }
      {
        float s1[4] = {0,0,0,0}, s2[4] = {0,0,0,0};
        #pragma unroll
        for (int nt = 0; nt < 4; ++nt){
          float bb = b1a[nt*16 + l15];
          #pragma unroll
          for (int i = 0; i < 4; ++i){
            float v = fmaxf(acc[nt][i] + bb, 0.f);
            acc[nt][i] = v; s1[i] += v; s2[i] += v*v;
          }
        }
        #pragma unroll
        for (int i = 0; i < 4; ++i){
          #pragma unroll
          for (int m = 1; m < 16; m <<= 1){ s1[i] += __shfl_xor(s1[i], m); s2[i] += __shfl_xor(s2[i], m); }
        }
        #pragma unroll
        for (int i = 0; i < 4; ++i){
          float mean = s1[i]*(1.f/64.f);
          float var  = s2[i]*(1.f/64.f) - mean*mean;
          float rs   = rsqrtf(var + 1e-5f);
          int row = wv*16 + quad*4 + i;
          #pragma unroll
          for (int nt = 0; nt < 4; ++nt){
            int ct = nt*16 + l15;
            A2s[row][ct] = f2bf((acc[nt][i] - mean)*rs*g1a[ct] + be1a[ct]);
          }
        }
      }
      __syncthreads();

      // mm2: (128 x 64) @ (64 x 64) -> write swizzled Arows[ct][d0+...]
      f32x4 acc2[4];
      #pragma unroll
      for (int nt = 0; nt < 4; ++nt) acc2[nt] = (f32x4){0.f,0.f,0.f,0.f};
      #pragma unroll
      for (int ks = 0; ks < 2; ++ks){
        s16x8 a = *(const s16x8*)&A2s[mrow][ks*32 + quad*8];
        #pragma unroll
        for (int nt = 0; nt < 4; ++nt)
          acc2[nt] = __builtin_amdgcn_mfma_f32_16x16x32_bf16(a, wb[nt*2 + ks], acc2[nt], 0, 0, 0);
      }
      {
        float s1[4] = {0,0,0,0}, s2[4] = {0,0,0,0};
        #pragma unroll
        for (int nt = 0; nt < 4; ++nt){
          float bb = b1b[nt*16 + l15];
          #pragma unroll
          for (int i = 0; i < 4; ++i){
            float v = fmaxf(acc2[nt][i] + bb, 0.f);
            acc2[nt][i] = v; s1[i] += v; s2[i] += v*v;
          }
        }
        #pragma unroll
        for (int i = 0; i < 4; ++i){
          #pragma unroll
          for (int m = 1; m < 16; m <<= 1){ s1[i] += __shfl_xor(s1[i], m); s2[i] += __shfl_xor(s2[i], m); }
        }
        #pragma unroll
        for (int i = 0; i < 4; ++i){
          float mean = s1[i]*(1.f/64.f);
          float var  = s2[i]*(1.f/64.f) - mean*mean;
          float rs   = rsqrtf(var + 1e-5f);
          int drow = wv*16 + quad*4 + i;           // d-index within chunk
          #pragma unroll
          for (int nt = 0; nt < 4; ++nt){
            int ct = nt*16 + l15;
            Arows[ar_idx(ct, d0 + drow)] = f2bf((acc2[nt][i] - mean)*rs*g1b[ct] + be1b[ct]);
          }
        }
      }
      __syncthreads();
    }
  }

  // ================= pass 3: mlp_2, A already in LDS =================
  gemm_ln_768<false>(Wpka, b2a, g2a, be2a, Arows, red, redt, out, b*64, t);
  __syncthreads();
  gemm_ln_768<true >(Wpkb, b2b, g2b, be2b, Arows, red, redt, out, b*64, t);
}

// ---------------------------------------------------------------------------
extern "C" void kernel_launch(void* const* d_in, const int* in_sizes, int n_in,
                              void* d_out, int out_size, void* d_ws, size_t ws_size,
                              hipStream_t stream){
  (void)in_sizes; (void)n_in; (void)out_size; (void)ws_size;
  const float* xe     = (const float*)d_in[0];
  const float* prompt = (const float*)d_in[1];
  const float* w1a = (const float*)d_in[2],  *b1a = (const float*)d_in[3];
  const float* g1a = (const float*)d_in[4],  *be1a= (const float*)d_in[5];
  const float* w1b = (const float*)d_in[6],  *b1b = (const float*)d_in[7];
  const float* g1b = (const float*)d_in[8],  *be1b= (const float*)d_in[9];
  const float* w2a = (const float*)d_in[10], *b2a = (const float*)d_in[11];
  const float* g2a = (const float*)d_in[12], *be2a= (const float*)d_in[13];
  const float* w2b = (const float*)d_in[14], *b2b = (const float*)d_in[15];
  const float* g2b = (const float*)d_in[16], *be2b= (const float*)d_in[17];
  float* out = (float*)d_out;

  char* ws = (char*)d_ws;
  u16*   Wpka   = (u16*)(ws);                      // 768x768 bf16 packed = 1179648 B
  u16*   Wpkb   = (u16*)(ws + 1179648);
  u16*   w1aT   = (u16*)(ws + 2359296);            // 64x96 bf16 packed
  u16*   w1bT   = (u16*)(ws + 2371584);            // 64x64 bf16 packed
  float* pnorm2 = (float*)(ws + 2379776);          // 30 f32

  hipMemsetAsync((char*)d_out + OUT_RSIM*sizeof(float), 0, sizeof(float), stream);
  prep_small<<<3, 256, 0, stream>>>(prompt, w1a, w1b, pnorm2, w1aT, w1bT);
  pack_w<<<dim3(48,24,2), 64, 0, stream>>>(w2a, w2b, Wpka, Wpkb);
  fused<<<B_, 512, 0, stream>>>(xe, prompt, pnorm2, w1aT, w1bT,
                                b1a, g1a, be1a, b1b, g1b, be1b,
                                Wpka, Wpkb,
                                b2a, g2a, be2a, b2b, g2b, be2b, out);
}